// Round 7
// baseline (115.560 us; speedup 1.0000x reference)
//
#include <hip/hip_runtime.h>
#include <math.h>

static constexpr int BLK = 256;
static constexpr int R = 8;        // queries per thread
static constexpr int TILE = 256;   // scan points staged per LDS tile
static constexpr int TP = TILE / 2; // packed scan-point pairs per tile
static constexpr float BIGW = 1e30f; // finite sentinel

typedef float f32x2 __attribute__((ext_vector_type(2)));
typedef float f32x4 __attribute__((ext_vector_type(4)));

__device__ __forceinline__ unsigned f2u(float f) { return __float_as_uint(f); }
__device__ __forceinline__ float u2f(unsigned u) { return __uint_as_float(u); }

// prep: sentinels + out=0 (288 KB ws; poison-as-sentinel rejected: correctness
// call's ws state is not documented as poisoned).
__global__ void prep_kernel(unsigned long long* __restrict__ o2s,
                            unsigned* __restrict__ s2o,
                            float* __restrict__ out, int N, int M) {
    int i = blockIdx.x * blockDim.x + threadIdx.x;
    if (i < N) o2s[i] = ~0ull;
    if (i < M) s2o[i] = 0xFFFFFFFFu;
    if (i == 0) out[0] = 0.0f;
}

// Stage TILE scan points into LDS as pair-interleaved records:
// record r (32 B) = [x0 x1 y0 y1 z0 z1 w0 w1] for points 2r, 2r+1.
// Read back as two f32x4: a={x0,x1,y0,y1}, b={z0,z1,w0,w1}.
__device__ __forceinline__ void stage_tile(float* lds, const float* __restrict__ pts,
                                           int base, int count) {
    int idx = base + (int)threadIdx.x;
    float x = 0.f, y = 0.f, z = 0.f, w = BIGW;
    if (idx < count) {
        x = pts[3 * idx]; y = pts[3 * idx + 1]; z = pts[3 * idx + 2];
        w = 0.5f * (x * x + y * y + z * z);
    }
    int r = threadIdx.x >> 1, h = threadIdx.x & 1;
    int o = r * 8 + h;
    lds[o + 0] = x;
    lds[o + 2] = y;
    lds[o + 4] = z;
    lds[o + 6] = w;
}

// Fused bidirectional NN scan, packed-f32 (v_pk_fma_f32) over scan-point pairs.
// min over d2 == min over m = 0.5|scan|^2 - qry.scan ; d2 = 2*(0.5|qry|^2 + m)
__global__ void __launch_bounds__(BLK) main_kernel(
    const float* __restrict__ P, const float* __restrict__ Ps,
    unsigned long long* __restrict__ o2s, unsigned* __restrict__ s2o,
    int N, int M, int o2sX, int o2sBlocks, int s2oX) {
    __shared__ f32x4 tile[TP * 2];
    float* lds = (float*)tile;
    int bx = blockIdx.x;

    if (bx < o2sBlocks) {
        // ---- original -> sampled: queries = P (N), scan = Ps (M), min+argmin ----
        int ix = bx % o2sX, iy = bx / o2sX;
        int ibase = ix * (BLK * R) + threadIdx.x;
        int j0 = iy * TILE;
        f32x2 px[R], py[R], pz[R];   // hoisted broadcasts {-c,-c}
        float pw[R], mnLo[R], mnHi[R];
#pragma unroll
        for (int r = 0; r < R; ++r) {
            int i = ibase + r * BLK;
            float x = 0.f, y = 0.f, z = 0.f;
            if (i < N) { x = P[3 * i]; y = P[3 * i + 1]; z = P[3 * i + 2]; }
            px[r] = (f32x2){-x, -x};
            py[r] = (f32x2){-y, -y};
            pz[r] = (f32x2){-z, -z};
            pw[r] = 0.5f * (x * x + y * y + z * z);
            mnLo[r] = __builtin_inff();
            mnHi[r] = __builtin_inff();
        }
        stage_tile(lds, Ps, j0, M);
        __syncthreads();
#pragma unroll 4
        for (int ii = 0; ii < TP; ++ii) {
            f32x4 a = tile[2 * ii], b = tile[2 * ii + 1];
            f32x2 sx = __builtin_shufflevector(a, a, 0, 1);
            f32x2 sy = __builtin_shufflevector(a, a, 2, 3);
            f32x2 sz = __builtin_shufflevector(b, b, 0, 1);
            f32x2 sw = __builtin_shufflevector(b, b, 2, 3);
            unsigned iLo = 2 * ii, iHi = 2 * ii + 1;
#pragma unroll
            for (int r = 0; r < R; ++r) {
                f32x2 m2 = __builtin_elementwise_fma(sx, px[r],
                            __builtin_elementwise_fma(sy, py[r],
                             __builtin_elementwise_fma(sz, pz[r], sw)));
                // pack pair-local index into low 8 mantissa bits; min tracks both
                float mpLo = u2f((f2u(m2.x) & 0xFFFFFF00u) | iLo);
                float mpHi = u2f((f2u(m2.y) & 0xFFFFFF00u) | iHi);
                mnLo[r] = fminf(mnLo[r], mpLo);
                mnHi[r] = fminf(mnHi[r], mpHi);
            }
        }
#pragma unroll
        for (int r = 0; r < R; ++r) {
            int i = ibase + r * BLK;
            if (i < N) {
                float mm = fminf(mnLo[r], mnHi[r]);
                unsigned j = (unsigned)j0 + (f2u(mm) & 0xFFu);
                float d2 = fmaxf(2.0f * (pw[r] + mm), 0.0f);
                atomicMin(&o2s[i], ((unsigned long long)f2u(d2) << 32) | j);
            }
        }
    } else {
        // ---- sampled -> original: queries = Ps (M), scan = P (N), min only ----
        int b = bx - o2sBlocks;
        int ix = b % s2oX, iy = b / s2oX;
        int jbase = ix * (BLK * R) + threadIdx.x;
        int i0 = iy * TILE;
        f32x2 qx[R], qy[R], qz[R];
        float qw[R];
        f32x2 mn[R];
#pragma unroll
        for (int r = 0; r < R; ++r) {
            int j = jbase + r * BLK;
            float x = 0.f, y = 0.f, z = 0.f;
            if (j < M) { x = Ps[3 * j]; y = Ps[3 * j + 1]; z = Ps[3 * j + 2]; }
            qx[r] = (f32x2){-x, -x};
            qy[r] = (f32x2){-y, -y};
            qz[r] = (f32x2){-z, -z};
            qw[r] = 0.5f * (x * x + y * y + z * z);
            mn[r] = (f32x2){__builtin_inff(), __builtin_inff()};
        }
        stage_tile(lds, P, i0, N);
        __syncthreads();
#pragma unroll 4
        for (int ii = 0; ii < TP; ++ii) {
            f32x4 a = tile[2 * ii], b2 = tile[2 * ii + 1];
            f32x2 sx = __builtin_shufflevector(a, a, 0, 1);
            f32x2 sy = __builtin_shufflevector(a, a, 2, 3);
            f32x2 sz = __builtin_shufflevector(b2, b2, 0, 1);
            f32x2 sw = __builtin_shufflevector(b2, b2, 2, 3);
#pragma unroll
            for (int r = 0; r < R; ++r) {
                f32x2 m2 = __builtin_elementwise_fma(sx, qx[r],
                            __builtin_elementwise_fma(sy, qy[r],
                             __builtin_elementwise_fma(sz, qz[r], sw)));
                mn[r].x = fminf(mn[r].x, m2.x);
                mn[r].y = fminf(mn[r].y, m2.y);
            }
        }
#pragma unroll
        for (int r = 0; r < R; ++r) {
            int j = jbase + r * BLK;
            if (j < M) {
                float mm = fminf(mn[r].x, mn[r].y);
                float d2 = fmaxf(2.0f * (qw[r] + mm), 0.0f);
                atomicMin(&s2o[j], f2u(d2));
            }
        }
    }
}

// finish: one load per query, weight, block-reduce, one atomicAdd per block.
__global__ void finish_kernel(const unsigned* __restrict__ s2o,
                              const unsigned long long* __restrict__ o2s,
                              const float* __restrict__ prob,
                              float* __restrict__ out, int N, int M) {
    int t = blockIdx.x * BLK + threadIdx.x;
    float acc = 0.0f;
    if (t < M) {
        acc = sqrtf(u2f(s2o[t])) * prob[t];
    } else if (t < M + N) {
        unsigned long long key = o2s[t - M];
        float d2 = u2f((unsigned)(key >> 32));
        unsigned jj = (unsigned)(key & 0xFFFFFFFFu);
        acc = sqrtf(d2) * prob[jj];
    }
#pragma unroll
    for (int off = 32; off > 0; off >>= 1) acc += __shfl_down(acc, off, 64);
    __shared__ float wsum[BLK / 64];
    int lane = threadIdx.x & 63, wave = threadIdx.x >> 6;
    if (lane == 0) wsum[wave] = acc;
    __syncthreads();
    if (threadIdx.x == 0) {
        float s = 0.0f;
#pragma unroll
        for (int w = 0; w < BLK / 64; ++w) s += wsum[w];
        atomicAdd(out, s);
    }
}

extern "C" void kernel_launch(void* const* d_in, const int* in_sizes, int n_in,
                              void* d_out, int out_size, void* d_ws, size_t ws_size,
                              hipStream_t stream) {
    const float* P = (const float*)d_in[0];
    const float* Ps = (const float*)d_in[1];
    const float* prob = (const float*)d_in[2];
    int N = in_sizes[0] / 3;  // 32768
    int M = in_sizes[1] / 3;  // 8192
    float* out = (float*)d_out;

    unsigned long long* o2s = (unsigned long long*)d_ws;       // N * 8 B
    unsigned* s2o = (unsigned*)((char*)d_ws + (size_t)N * 8);  // M * 4 B

    int o2sX = (N + BLK * R - 1) / (BLK * R);   // 16
    int o2sY = (M + TILE - 1) / TILE;           // 32
    int s2oX = (M + BLK * R - 1) / (BLK * R);   // 4
    int s2oY = (N + TILE - 1) / TILE;           // 128
    int o2sBlocks = o2sX * o2sY;                // 512
    int total = o2sBlocks + s2oX * s2oY;        // 1024 = 4 blocks/CU

    prep_kernel<<<(N + BLK - 1) / BLK, BLK, 0, stream>>>(o2s, s2o, out, N, M);
    main_kernel<<<total, BLK, 0, stream>>>(P, Ps, o2s, s2o, N, M,
                                           o2sX, o2sBlocks, s2oX);
    finish_kernel<<<(N + M + BLK - 1) / BLK, BLK, 0, stream>>>(s2o, o2s, prob,
                                                               out, N, M);
}

// Round 8
// 108.134 us; speedup vs baseline: 1.0687x; 1.0687x over previous
//
#include <hip/hip_runtime.h>
#include <math.h>

static constexpr int BLK = 256;
static constexpr int R = 8;      // queries per thread
static constexpr int TILE = 256; // scan points staged in LDS per block
static constexpr float BIGW = 1e30f;  // finite sentinel

__device__ __forceinline__ unsigned f2u(float f) { return __float_as_uint(f); }
__device__ __forceinline__ float u2f(unsigned u) { return __uint_as_float(u); }

// prep: sentinels + out=0 (288 KB ws).
__global__ void prep_kernel(unsigned long long* __restrict__ o2s,
                            unsigned* __restrict__ s2o,
                            float* __restrict__ out, int N, int M) {
    int i = blockIdx.x * blockDim.x + threadIdx.x;
    if (i < N) o2s[i] = ~0ull;
    if (i < M) s2o[i] = 0xFFFFFFFFu;
    if (i == 0) out[0] = 0.0f;
}

// Fused bidirectional NN scan (scalar VALU — pk_fma regressed in R6/R7).
// min over d2 == min over m = 0.5|scan|^2 - qry.scan ; d2 = 2*(0.5|qry|^2 + m)
// o2s argmin: tile-local index packed into low 8 mantissa bits of m
// (v_and_or_b32 + v_min); 2 points/iter folded via fminf(fminf(..)) -> v_min3.
__global__ void __launch_bounds__(BLK) main_kernel(
    const float* __restrict__ P, const float* __restrict__ Ps,
    unsigned long long* __restrict__ o2s, unsigned* __restrict__ s2o,
    int N, int M, int o2sX, int o2sBlocks, int s2oX) {
    __shared__ float4 tile[TILE];
    int bx = blockIdx.x;

    if (bx < o2sBlocks) {
        // ---- original -> sampled: queries = P (N), scan = Ps (M), min+argmin ----
        int ix = bx % o2sX, iy = bx / o2sX;
        int ibase = ix * (BLK * R) + threadIdx.x;
        int j0 = iy * TILE;
        float4 p[R];
        float mmin[R];
#pragma unroll
        for (int r = 0; r < R; ++r) {
            int i = ibase + r * BLK;
            float x = 0.f, y = 0.f, z = 0.f;
            if (i < N) { x = P[3 * i]; y = P[3 * i + 1]; z = P[3 * i + 2]; }
            p[r] = make_float4(-x, -y, -z, 0.5f * (x * x + y * y + z * z));
            mmin[r] = __builtin_inff();
        }
        {
            int idx = j0 + threadIdx.x;
            float x = 0.f, y = 0.f, z = 0.f, w = BIGW;
            if (idx < M) {
                x = Ps[3 * idx]; y = Ps[3 * idx + 1]; z = Ps[3 * idx + 2];
                w = 0.5f * (x * x + y * y + z * z);
            }
            tile[threadIdx.x] = make_float4(x, y, z, w);
        }
        __syncthreads();
#pragma unroll 4
        for (int ii = 0; ii < TILE; ii += 2) {
            float4 qa = tile[ii];
            float4 qb = tile[ii + 1];
#pragma unroll
            for (int r = 0; r < R; ++r) {
                float ma = fmaf(qa.x, p[r].x, fmaf(qa.y, p[r].y, fmaf(qa.z, p[r].z, qa.w)));
                float mb = fmaf(qb.x, p[r].x, fmaf(qb.y, p[r].y, fmaf(qb.z, p[r].z, qb.w)));
                float pa = u2f((f2u(ma) & 0xFFFFFF00u) | (unsigned)ii);
                float pb = u2f((f2u(mb) & 0xFFFFFF00u) | (unsigned)(ii + 1));
                mmin[r] = fminf(fminf(mmin[r], pa), pb);  // -> v_min3_f32
            }
        }
#pragma unroll
        for (int r = 0; r < R; ++r) {
            int i = ibase + r * BLK;
            if (i < N) {
                unsigned j = (unsigned)j0 + (f2u(mmin[r]) & 0xFFu);
                float d2 = fmaxf(2.0f * (p[r].w + mmin[r]), 0.0f);
                atomicMin(&o2s[i], ((unsigned long long)f2u(d2) << 32) | j);
            }
        }
    } else {
        // ---- sampled -> original: queries = Ps (M), scan = P (N), min only ----
        int b = bx - o2sBlocks;
        int ix = b % s2oX, iy = b / s2oX;
        int jbase = ix * (BLK * R) + threadIdx.x;
        int i0 = iy * TILE;
        float4 q[R];
        float mmin[R];
#pragma unroll
        for (int r = 0; r < R; ++r) {
            int j = jbase + r * BLK;
            float x = 0.f, y = 0.f, z = 0.f;
            if (j < M) { x = Ps[3 * j]; y = Ps[3 * j + 1]; z = Ps[3 * j + 2]; }
            q[r] = make_float4(-x, -y, -z, 0.5f * (x * x + y * y + z * z));
            mmin[r] = __builtin_inff();
        }
        {
            int idx = i0 + threadIdx.x;
            float x = 0.f, y = 0.f, z = 0.f, w = BIGW;
            if (idx < N) {
                x = P[3 * idx]; y = P[3 * idx + 1]; z = P[3 * idx + 2];
                w = 0.5f * (x * x + y * y + z * z);
            }
            tile[threadIdx.x] = make_float4(x, y, z, w);
        }
        __syncthreads();
#pragma unroll 4
        for (int ii = 0; ii < TILE; ii += 2) {
            float4 pa = tile[ii];
            float4 pb = tile[ii + 1];
#pragma unroll
            for (int r = 0; r < R; ++r) {
                float ma = fmaf(pa.x, q[r].x, fmaf(pa.y, q[r].y, fmaf(pa.z, q[r].z, pa.w)));
                float mb = fmaf(pb.x, q[r].x, fmaf(pb.y, q[r].y, fmaf(pb.z, q[r].z, pb.w)));
                mmin[r] = fminf(fminf(mmin[r], ma), mb);  // -> v_min3_f32
            }
        }
#pragma unroll
        for (int r = 0; r < R; ++r) {
            int j = jbase + r * BLK;
            if (j < M) {
                float d2 = fmaxf(2.0f * (q[r].w + mmin[r]), 0.0f);
                atomicMin(&s2o[j], f2u(d2));
            }
        }
    }
}

// finish: one load per query, weight, block-reduce, one atomicAdd per block.
__global__ void finish_kernel(const unsigned* __restrict__ s2o,
                              const unsigned long long* __restrict__ o2s,
                              const float* __restrict__ prob,
                              float* __restrict__ out, int N, int M) {
    int t = blockIdx.x * BLK + threadIdx.x;
    float acc = 0.0f;
    if (t < M) {
        acc = sqrtf(u2f(s2o[t])) * prob[t];
    } else if (t < M + N) {
        unsigned long long key = o2s[t - M];
        float d2 = u2f((unsigned)(key >> 32));
        unsigned jj = (unsigned)(key & 0xFFFFFFFFu);
        acc = sqrtf(d2) * prob[jj];
    }
#pragma unroll
    for (int off = 32; off > 0; off >>= 1) acc += __shfl_down(acc, off, 64);
    __shared__ float wsum[BLK / 64];
    int lane = threadIdx.x & 63, wave = threadIdx.x >> 6;
    if (lane == 0) wsum[wave] = acc;
    __syncthreads();
    if (threadIdx.x == 0) {
        float s = 0.0f;
#pragma unroll
        for (int w = 0; w < BLK / 64; ++w) s += wsum[w];
        atomicAdd(out, s);
    }
}

extern "C" void kernel_launch(void* const* d_in, const int* in_sizes, int n_in,
                              void* d_out, int out_size, void* d_ws, size_t ws_size,
                              hipStream_t stream) {
    const float* P = (const float*)d_in[0];
    const float* Ps = (const float*)d_in[1];
    const float* prob = (const float*)d_in[2];
    int N = in_sizes[0] / 3;  // 32768
    int M = in_sizes[1] / 3;  // 8192
    float* out = (float*)d_out;

    unsigned long long* o2s = (unsigned long long*)d_ws;       // N * 8 B
    unsigned* s2o = (unsigned*)((char*)d_ws + (size_t)N * 8);  // M * 4 B

    int o2sX = (N + BLK * R - 1) / (BLK * R);   // 16
    int o2sY = (M + TILE - 1) / TILE;           // 32
    int s2oX = (M + BLK * R - 1) / (BLK * R);   // 4
    int s2oY = (N + TILE - 1) / TILE;           // 128
    int o2sBlocks = o2sX * o2sY;                // 512
    int total = o2sBlocks + s2oX * s2oY;        // 1024 = 4 blocks/CU

    prep_kernel<<<(N + BLK - 1) / BLK, BLK, 0, stream>>>(o2s, s2o, out, N, M);
    main_kernel<<<total, BLK, 0, stream>>>(P, Ps, o2s, s2o, N, M,
                                           o2sX, o2sBlocks, s2oX);
    finish_kernel<<<(N + M + BLK - 1) / BLK, BLK, 0, stream>>>(s2o, o2s, prob,
                                                               out, N, M);
}